// Round 1
// baseline (67.625 us; speedup 1.0000x reference)
//
#include <hip/hip_runtime.h>

// YOLO v1 loss on MI355X.
// Layout: bounding_boxes (BATCH,7,7,30) f32, ground_truth (BATCH,7,7,30) f32.
// Output: 6 float32 scalars {loss, loss_coord, loss_confidence, loss_classes,
//                            iou_sum, object_num}.

#define CH 30
#define TILE 256            // cells per block-tile
#define NCELLS (8192 * 49)  // 401408
#define NTILES (NCELLS / TILE)  // 1568 exactly
#define GRID_BLOCKS 512

__device__ __forceinline__ float iou_one(const float* __restrict__ B,
                                         const float* __restrict__ G,
                                         float fx, float fy) {
    float px = truncf((B[0] + fx) * 64.0f);
    float py = truncf((B[1] + fy) * 64.0f);
    float pw = truncf(B[2] * 448.0f);
    float ph = truncf(B[3] * 448.0f);
    float x1 = fmaxf(0.0f, px - pw * 0.5f);
    float y1 = fmaxf(0.0f, py - ph * 0.5f);
    float x2 = fminf(447.0f, px + pw * 0.5f);
    float y2 = fminf(447.0f, py + ph * 0.5f);
    float parea = (x2 - x1) * (y2 - y1);
    float lx = fmaxf(x1, G[5]);
    float rx = fminf(x2, G[7]);
    float uy = fmaxf(y1, G[6]);
    float dy = fminf(y2, G[8]);
    float inter = (rx - lx) * (dy - uy);
    bool valid = (rx >= lx) && (dy >= uy);
    return valid ? inter / (parea + G[9] - inter) : 0.0f;
}

__global__ __launch_bounds__(256) void yolo_v1_loss_kernel(
    const float* __restrict__ bb, const float* __restrict__ gt,
    float* __restrict__ out) {
    __shared__ float sBB[TILE * CH];  // 30720 B
    __shared__ float sGT[TILE * CH];  // 30720 B
    __shared__ float sRed[4][6];

    const int tid = threadIdx.x;
    float a_loss = 0.f, a_coord = 0.f, a_conf = 0.f, a_cls = 0.f,
          a_iou = 0.f, a_obj = 0.f;

    for (int tile = blockIdx.x; tile < NTILES; tile += gridDim.x) {
        __syncthreads();  // protect LDS from previous iteration's readers
        // ---- coalesced staging: 1920 float4 per array ----
        const float4* g0 = (const float4*)(bb + (size_t)tile * TILE * CH);
        const float4* g1 = (const float4*)(gt + (size_t)tile * TILE * CH);
        float4* s0 = (float4*)sBB;
        float4* s1 = (float4*)sGT;
#pragma unroll
        for (int i = 0; i < 8; ++i) {
            int idx = tid + i * 256;
            if (idx < (TILE * CH) / 4) {
                s0[idx] = g0[idx];
                s1[idx] = g1[idx];
            }
        }
        __syncthreads();

        // ---- per-cell math ----
        int cell = tile * TILE + tid;
        int b = cell / 49;
        int rem = cell - b * 49;
        int gy = rem / 7;
        int gx = rem - gy * 7;
        float fx = (float)gx, fy = (float)gy;

        const float* B = sBB + tid * CH;
        const float* G = sGT + tid * CH;

        float iou1 = iou_one(B, G, fx, fy);
        float iou2 = iou_one(B + 5, G, fx, fy);
        bool r1 = iou1 > iou2;
        const float* P = r1 ? B : (B + 5);       // responsible box
        const float* Nb = r1 ? (B + 5) : B;      // other box
        float iou = r1 ? iou1 : iou2;

        float fm = (rintf(G[4]) != 0.0f) ? 1.0f : 0.0f;

        float noobj = 0.5f * (B[4] * B[4] + B[9] * B[9]);

        float dx = P[0] - G[0];
        float dyv = P[1] - G[1];
        float dw = sqrtf(P[2]) - sqrtf(G[2]);
        float dh = sqrtf(P[3]) - sqrtf(G[3]);
        float coord = 5.0f * (dx * dx + dyv * dyv + dw * dw + dh * dh);

        float dc = P[4] - iou;
        float conf = dc * dc + 0.5f * Nb[4] * Nb[4];

        float cls = 0.f;
#pragma unroll
        for (int k = 0; k < 20; ++k) {
            float d = G[10 + k] - B[10 + k];
            cls += d * d;
        }

        float ifm = 1.0f - fm;
        a_loss += fm * (coord + conf + cls) + ifm * noobj;
        a_coord += fm * coord;
        a_conf += fm * conf + ifm * noobj;
        a_cls += fm * cls;
        a_iou += fm * iou;
        a_obj += fm;
    }

    // ---- wave reduce (64-wide) ----
#pragma unroll
    for (int off = 32; off > 0; off >>= 1) {
        a_loss += __shfl_down(a_loss, off);
        a_coord += __shfl_down(a_coord, off);
        a_conf += __shfl_down(a_conf, off);
        a_cls += __shfl_down(a_cls, off);
        a_iou += __shfl_down(a_iou, off);
        a_obj += __shfl_down(a_obj, off);
    }
    int wave = tid >> 6;
    int lane = tid & 63;
    if (lane == 0) {
        sRed[wave][0] = a_loss;
        sRed[wave][1] = a_coord;
        sRed[wave][2] = a_conf;
        sRed[wave][3] = a_cls;
        sRed[wave][4] = a_iou;
        sRed[wave][5] = a_obj;
    }
    __syncthreads();
    if (tid == 0) {
#pragma unroll
        for (int j = 0; j < 6; ++j) {
            float v = sRed[0][j] + sRed[1][j] + sRed[2][j] + sRed[3][j];
            atomicAdd(&out[j], v);
        }
    }
}

extern "C" void kernel_launch(void* const* d_in, const int* in_sizes, int n_in,
                              void* d_out, int out_size, void* d_ws,
                              size_t ws_size, hipStream_t stream) {
    const float* bb = (const float*)d_in[0];
    const float* gt = (const float*)d_in[1];
    float* out = (float*)d_out;
    hipMemsetAsync(out, 0, out_size * sizeof(float), stream);
    yolo_v1_loss_kernel<<<GRID_BLOCKS, 256, 0, stream>>>(bb, gt, out);
}